// Round 2
// 823.869 us; speedup vs baseline: 1.0036x; 1.0036x over previous
//
#include <hip/hip_runtime.h>

using u16 = unsigned short;
using u32 = unsigned int;

typedef __bf16 v8bf __attribute__((ext_vector_type(8)));
typedef float  v4f  __attribute__((ext_vector_type(4)));

#define ST  68    // u16 stride for agg stage rows (34 dwords: 2-way max aliasing)
#define STK 132   // u16 stride for 128-wide bf16 LDS rows
#define EPB 128   // edges per block in agg_k / ewmlp_k
#define RW  6     // record width in u32: [0..3]=ea bf16x8, [4]=src, [5]=tgt (old path)

__device__ __forceinline__ u16 f2b(float f){
  u32 u = __builtin_bit_cast(u32, f);
  u += 0x7FFFu + ((u >> 16) & 1u);
  return (u16)(u >> 16);
}
__device__ __forceinline__ float b2f(u16 b){
  u32 u = ((u32)b) << 16;
  return __builtin_bit_cast(float, u);
}
__device__ __forceinline__ u32 pk2(float lo, float hi){
  return ((u32)f2b(hi) << 16) | f2b(lo);
}

union bfu { v8bf v; u16 s[8]; u32 w[4]; };

__device__ __forceinline__ v8bf zero8(){
  bfu u;
  #pragma unroll
  for (int i = 0; i < 4; i++) u.w[i] = 0;
  return u.v;
}

// ---------------- counting sort by target ----------------

__global__ __launch_bounds__(256) void hist_k(const int* __restrict__ col, int* __restrict__ counts, int E){
  int e = blockIdx.x*256 + threadIdx.x;
  if (e < E) atomicAdd(&counts[col[e]], 1);
}

__global__ __launch_bounds__(1024) void scan1_k(const int* __restrict__ counts, int* __restrict__ start,
                                                int* __restrict__ bsum, int N){
  __shared__ int s[1024];
  int tid = threadIdx.x;
  int i = blockIdx.x*1024 + tid;
  int v = (i < N) ? counts[i] : 0;
  s[tid] = v; __syncthreads();
  for (int off = 1; off < 1024; off <<= 1){
    int t = (tid >= off) ? s[tid-off] : 0;
    __syncthreads();
    s[tid] += t;
    __syncthreads();
  }
  if (i < N) start[i] = s[tid] - v;
  if (tid == 1023) bsum[blockIdx.x] = s[1023];
}

__global__ __launch_bounds__(1024) void scan2_k(int* __restrict__ bsum, int nb, int* __restrict__ start,
                                                int N, int E){
  __shared__ int s[1024];
  int tid = threadIdx.x;
  int v = (tid < nb) ? bsum[tid] : 0;
  s[tid] = v; __syncthreads();
  for (int off = 1; off < 1024; off <<= 1){
    int t = (tid >= off) ? s[tid-off] : 0;
    __syncthreads();
    s[tid] += t;
    __syncthreads();
  }
  if (tid < nb) bsum[tid] = s[tid] - v;
  if (tid == 0) start[N] = E;
}

__global__ __launch_bounds__(1024) void scan3_k(int* __restrict__ start, const int* __restrict__ bsum,
                                                int* __restrict__ cursor, int N){
  int i = blockIdx.x*1024 + threadIdx.x;
  if (i < N){
    int v = start[i] + bsum[blockIdx.x];
    start[i] = v;
    cursor[i] = v;
  }
}

// old-path fused scatter: one 24B record per edge {ea bf16x8, src, tgt} into sorted slot
__global__ __launch_bounds__(256) void scat_k(const int* __restrict__ row, const int* __restrict__ col,
                                              const float* __restrict__ ea, int* __restrict__ cursor,
                                              u32* __restrict__ rec, int E){
  int e = blockIdx.x*256 + threadIdx.x;
  if (e < E){
    int c = col[e];
    int s = row[e];
    const float4* eap = (const float4*)(ea + (size_t)e*8);
    float4 a0 = eap[0], a1 = eap[1];
    u32 w0 = pk2(a0.x, a0.y), w1 = pk2(a0.z, a0.w);
    u32 w2 = pk2(a1.x, a1.y), w3 = pk2(a1.z, a1.w);
    int p = atomicAdd(&cursor[c], 1);
    int2* r2 = (int2*)(rec + (size_t)p*RW);   // 8B aligned (24B stride)
    r2[0] = make_int2((int)w0, (int)w1);
    r2[1] = make_int2((int)w2, (int)w3);
    r2[2] = make_int2(s, c);
  }
}

// new-path scatter: eas = sorted bf16x8 edge attrs (16B), rp = sorted (src,tgt) pairs (8B)
__global__ __launch_bounds__(256) void scat2_k(const int* __restrict__ row, const int* __restrict__ col,
                                               const float* __restrict__ ea, int* __restrict__ cursor,
                                               u32* __restrict__ eas, int2* __restrict__ rp, int E){
  int e = blockIdx.x*256 + threadIdx.x;
  if (e < E){
    int c = col[e];
    int s = row[e];
    const float4* eap = (const float4*)(ea + (size_t)e*8);
    float4 a0 = eap[0], a1 = eap[1];
    u32 w0 = pk2(a0.x, a0.y), w1 = pk2(a0.z, a0.w);
    u32 w2 = pk2(a1.x, a1.y), w3 = pk2(a1.z, a1.w);
    int p = atomicAdd(&cursor[c], 1);
    ((int4*)eas)[p] = make_int4((int)w0, (int)w1, (int)w2, (int)w3);
    rp[p] = make_int2(s, c);
  }
}

// ---------------- old path: fused edge-MLP + segmented aggregation ----------------

template<int MODE>   // 0: degree (xv=1)   1: layer (gather V bf16)
__global__ __launch_bounds__(256) void agg_k(const u32* __restrict__ rec, const float* __restrict__ W1,
                                             const float* __restrict__ W2,
                                             const u16* __restrict__ V, float* __restrict__ U, int E){
  __shared__ __align__(16) u16 stage[EPB*ST];
  __shared__ __align__(16) u16 w2s[64*ST];
  __shared__ __align__(16) u16 w1s[64*32];
  __shared__ int sl[EPB], tl[EPB];
  int tid = threadIdx.x;
  int j0 = blockIdx.x*EPB;

  if (tid < EPB){
    int j = j0 + tid;
    int2 a = make_int2(0,0), b = make_int2(0,0), c = make_int2(0,0);
    if (j < E){
      const int2* r2 = (const int2*)(rec + (size_t)j*RW);
      a = r2[0]; b = r2[1]; c = r2[2];
    }
    sl[tid] = c.x;
    tl[tid] = c.y;
    *(int2*)&stage[tid*ST]     = a;
    *(int2*)&stage[tid*ST + 4] = b;
  }
  for (int i = tid; i < 2048; i += 256){ int r = i >> 5, k = i & 31; w1s[i] = (k < 8) ? f2b(W1[r*8+k]) : (u16)0; }
  for (int i = tid; i < 4096; i += 256){ w2s[(i>>6)*ST + (i&63)] = f2b(W2[i]); }
  __syncthreads();

  int w = tid >> 6, lane = tid & 63;
  int m16 = lane & 15, quad = lane >> 4;
  int base = w*32;

  v8bf af1[2];
  #pragma unroll
  for (int mi = 0; mi < 2; mi++){
    af1[mi] = zero8();
    if (quad == 0){
      int rr = base + mi*16 + m16;
      int2 p0 = *(const int2*)&stage[rr*ST];
      int2 p1 = *(const int2*)&stage[rr*ST + 4];
      bfu u; u.w[0] = (u32)p0.x; u.w[1] = (u32)p0.y; u.w[2] = (u32)p1.x; u.w[3] = (u32)p1.y;
      af1[mi] = u.v;
    }
  }
  v4f acc1[2][4];
  #pragma unroll
  for (int mi = 0; mi < 2; mi++)
    #pragma unroll
    for (int ni = 0; ni < 4; ni++) acc1[mi][ni] = (v4f){0.f,0.f,0.f,0.f};
  #pragma unroll
  for (int ni = 0; ni < 4; ni++){
    v8bf bf = *(const v8bf*)&w1s[(ni*16 + m16)*32 + quad*8];
    #pragma unroll
    for (int mi = 0; mi < 2; mi++)
      acc1[mi][ni] = __builtin_amdgcn_mfma_f32_16x16x32_bf16(af1[mi], bf, acc1[mi][ni], 0, 0, 0);
  }
  #pragma unroll
  for (int mi = 0; mi < 2; mi++)
    #pragma unroll
    for (int ni = 0; ni < 4; ni++)
      #pragma unroll
      for (int r = 0; r < 4; r++)
        stage[(base + mi*16 + quad*4 + r)*ST + ni*16 + m16] = f2b(fmaxf(acc1[mi][ni][r], 0.f));

  v4f acc2[2][4];
  #pragma unroll
  for (int mi = 0; mi < 2; mi++)
    #pragma unroll
    for (int ni = 0; ni < 4; ni++) acc2[mi][ni] = (v4f){0.f,0.f,0.f,0.f};
  #pragma unroll
  for (int ks = 0; ks < 2; ks++){
    v8bf bf[4];
    #pragma unroll
    for (int ni = 0; ni < 4; ni++)
      bf[ni] = *(const v8bf*)&w2s[(ni*16 + m16)*ST + ks*32 + quad*8];
    #pragma unroll
    for (int mi = 0; mi < 2; mi++){
      v8bf af = *(const v8bf*)&stage[(base + mi*16 + m16)*ST + ks*32 + quad*8];
      #pragma unroll
      for (int ni = 0; ni < 4; ni++)
        acc2[mi][ni] = __builtin_amdgcn_mfma_f32_16x16x32_bf16(af, bf[ni], acc2[mi][ni], 0, 0, 0);
    }
  }
  #pragma unroll
  for (int mi = 0; mi < 2; mi++)
    #pragma unroll
    for (int ni = 0; ni < 4; ni++)
      #pragma unroll
      for (int r = 0; r < 4; r++)
        stage[(base + mi*16 + quad*4 + r)*ST + ni*16 + m16] = f2b(fmaxf(acc2[mi][ni][r], 0.f));

  int lim = E - (j0 + base); if (lim > 32) lim = 32;
  if (lim == 32){
    float s = 0.f;
    int cur = tl[base];
    #pragma unroll
    for (int q0 = 0; q0 < 32; q0 += 8){
      float wv[8], xv[8];
      #pragma unroll
      for (int q = 0; q < 8; q++){
        wv[q] = b2f(stage[(base+q0+q)*ST + lane]);
        xv[q] = MODE ? b2f(V[(size_t)sl[base+q0+q]*64 + lane]) : 1.f;
      }
      #pragma unroll
      for (int q = 0; q < 8; q++){
        int t = tl[base+q0+q];
        if (t != cur){ atomicAdd(&U[(size_t)cur*64 + lane], s); s = 0.f; cur = t; }
        s += wv[q]*xv[q];
      }
    }
    atomicAdd(&U[(size_t)cur*64 + lane], s);
  } else if (lim > 0){
    float s = 0.f;
    int cur = tl[base];
    for (int q = 0; q < lim; q++){
      float wv = b2f(stage[(base+q)*ST + lane]);
      float xv = MODE ? b2f(V[(size_t)sl[base+q]*64 + lane]) : 1.f;
      int t = tl[base+q];
      if (t != cur){ atomicAdd(&U[(size_t)cur*64 + lane], s); s = 0.f; cur = t; }
      s += wv*xv;
    }
    atomicAdd(&U[(size_t)cur*64 + lane], s);
  }
}

// ---------------- new path: edge-MLP once, ew stored transposed ----------------
// ews layout: per 32-edge group G: [64 channels][32 edges] u16  (4 KB/group)

__global__ __launch_bounds__(256) void ewmlp_k(const u32* __restrict__ eas, const float* __restrict__ W1,
                                               const float* __restrict__ W2, u16* __restrict__ ews, int E){
  __shared__ __align__(16) u16 stage[EPB*ST];
  __shared__ __align__(16) u16 w2s[64*ST];
  __shared__ __align__(16) u16 w1s[64*32];
  int tid = threadIdx.x;
  int j0 = blockIdx.x*EPB;

  if (tid < EPB){
    int j = j0 + tid;
    int4 a = make_int4(0,0,0,0);
    if (j < E) a = ((const int4*)eas)[j];
    *(int2*)&stage[tid*ST]     = make_int2(a.x, a.y);
    *(int2*)&stage[tid*ST + 4] = make_int2(a.z, a.w);
  }
  for (int i = tid; i < 2048; i += 256){ int r = i >> 5, k = i & 31; w1s[i] = (k < 8) ? f2b(W1[r*8+k]) : (u16)0; }
  for (int i = tid; i < 4096; i += 256){ w2s[(i>>6)*ST + (i&63)] = f2b(W2[i]); }
  __syncthreads();

  int w = tid >> 6, lane = tid & 63;
  int m16 = lane & 15, quad = lane >> 4;
  int base = w*32;

  // layer 1 via MFMA (K padded 8->32)
  v8bf af1[2];
  #pragma unroll
  for (int mi = 0; mi < 2; mi++){
    af1[mi] = zero8();
    if (quad == 0){
      int rr = base + mi*16 + m16;
      int2 p0 = *(const int2*)&stage[rr*ST];
      int2 p1 = *(const int2*)&stage[rr*ST + 4];
      bfu u; u.w[0] = (u32)p0.x; u.w[1] = (u32)p0.y; u.w[2] = (u32)p1.x; u.w[3] = (u32)p1.y;
      af1[mi] = u.v;
    }
  }
  v4f acc1[2][4];
  #pragma unroll
  for (int mi = 0; mi < 2; mi++)
    #pragma unroll
    for (int ni = 0; ni < 4; ni++) acc1[mi][ni] = (v4f){0.f,0.f,0.f,0.f};
  #pragma unroll
  for (int ni = 0; ni < 4; ni++){
    v8bf bf = *(const v8bf*)&w1s[(ni*16 + m16)*32 + quad*8];
    #pragma unroll
    for (int mi = 0; mi < 2; mi++)
      acc1[mi][ni] = __builtin_amdgcn_mfma_f32_16x16x32_bf16(af1[mi], bf, acc1[mi][ni], 0, 0, 0);
  }
  #pragma unroll
  for (int mi = 0; mi < 2; mi++)
    #pragma unroll
    for (int ni = 0; ni < 4; ni++)
      #pragma unroll
      for (int r = 0; r < 4; r++)
        stage[(base + mi*16 + quad*4 + r)*ST + ni*16 + m16] = f2b(fmaxf(acc1[mi][ni][r], 0.f));

  // layer 2 via MFMA (wave-local rows; per-wave DS ordering makes write->read safe)
  v4f acc2[2][4];
  #pragma unroll
  for (int mi = 0; mi < 2; mi++)
    #pragma unroll
    for (int ni = 0; ni < 4; ni++) acc2[mi][ni] = (v4f){0.f,0.f,0.f,0.f};
  #pragma unroll
  for (int ks = 0; ks < 2; ks++){
    v8bf bf[4];
    #pragma unroll
    for (int ni = 0; ni < 4; ni++)
      bf[ni] = *(const v8bf*)&w2s[(ni*16 + m16)*ST + ks*32 + quad*8];
    #pragma unroll
    for (int mi = 0; mi < 2; mi++){
      v8bf af = *(const v8bf*)&stage[(base + mi*16 + m16)*ST + ks*32 + quad*8];
      #pragma unroll
      for (int ni = 0; ni < 4; ni++)
        acc2[mi][ni] = __builtin_amdgcn_mfma_f32_16x16x32_bf16(af, bf[ni], acc2[mi][ni], 0, 0, 0);
    }
  }
  #pragma unroll
  for (int mi = 0; mi < 2; mi++)
    #pragma unroll
    for (int ni = 0; ni < 4; ni++)
      #pragma unroll
      for (int r = 0; r < 4; r++)
        stage[(base + mi*16 + quad*4 + r)*ST + ni*16 + m16] = f2b(fmaxf(acc2[mi][ni][r], 0.f));

  // transposed store: wave w owns rows [w*32, w*32+32) == group blockIdx*4+w.
  // thread = (group w, channel lane): pack 32 edges of its channel, 64B coalesced store.
  u32 wbuf[16];
  #pragma unroll
  for (int qq = 0; qq < 16; qq++){
    u32 lo = stage[(base + 2*qq    )*ST + lane];
    u32 hi = stage[(base + 2*qq + 1)*ST + lane];
    wbuf[qq] = lo | (hi << 16);
  }
  size_t G = (size_t)blockIdx.x*4 + w;
  uint4* dst = (uint4*)(ews + G*2048 + (size_t)lane*32);
  #pragma unroll
  for (int i = 0; i < 4; i++) dst[i] = *(const uint4*)&wbuf[i*4];
}

// slim aggregation: one wave = one 32-edge sorted group. lane = channel.
// scalar (src,tgt) via uniform loads; ew via 4x dwordx4; V prefetched to regs.
template<int MODE>
__global__ __launch_bounds__(256) void sagg_k(const u16* __restrict__ ews, const int2* __restrict__ rp,
                                              const u16* __restrict__ V, float* __restrict__ U, int E){
  int tid = threadIdx.x;
  int lane = tid & 63;
  int w = __builtin_amdgcn_readfirstlane(tid >> 6);
  int G = blockIdx.x*4 + w;
  int e0 = G*32;
  if (e0 >= E) return;
  int lim = E - e0; if (lim > 32) lim = 32;
  const int2* rpg = rp + e0;

  if (lim == 32){
    u32 ew[16];
    const uint4* ep = (const uint4*)(ews + (size_t)G*2048 + (size_t)lane*32);
    #pragma unroll
    for (int i = 0; i < 4; i++) *(uint4*)&ew[i*4] = ep[i];

    float xv[32];
    #pragma unroll
    for (int q = 0; q < 32; q++)
      xv[q] = MODE ? b2f(V[(size_t)rpg[q].x*64 + lane]) : 1.f;

    float s = 0.f;
    int cur = __builtin_amdgcn_readfirstlane(rpg[0].y);
    #pragma unroll
    for (int q = 0; q < 32; q++){
      int ty = __builtin_amdgcn_readfirstlane(rpg[q].y);
      if (ty != cur){ atomicAdd(&U[(size_t)cur*64 + lane], s); s = 0.f; cur = ty; }
      u32 wbits = (q & 1) ? (ew[q>>1] & 0xffff0000u) : (ew[q>>1] << 16);
      s += __builtin_bit_cast(float, wbits) * xv[q];
    }
    atomicAdd(&U[(size_t)cur*64 + lane], s);
  } else {
    float s = 0.f;
    int cur = rpg[0].y;
    for (int q = 0; q < lim; q++){
      int2 r = rpg[q];
      if (r.y != cur){ atomicAdd(&U[(size_t)cur*64 + lane], s); s = 0.f; cur = r.y; }
      float wv = b2f(ews[(size_t)G*2048 + (size_t)lane*32 + q]);
      float xvv = MODE ? b2f(V[(size_t)r.x*64 + lane]) : 1.f;
      s += wv*xvv;
    }
    atomicAdd(&U[(size_t)cur*64 + lane], s);
  }
}

__global__ __launch_bounds__(256) void degfin_k(float* __restrict__ U, float* __restrict__ dinv, int NH){
  int i = blockIdx.x*256 + threadIdx.x;
  if (i < NH){
    dinv[i] = rsqrtf(1.f + U[i]);
    U[i] = 0.f;
  }
}

// ---------------- xlin via MFMA: 64 nodes/block; xlin stored bf16 ----------------

__global__ __launch_bounds__(256) void xlin_k(const float* __restrict__ x, const float* __restrict__ Wi,
                                              const float* __restrict__ bi, const float* __restrict__ wconv0,
                                              const float* __restrict__ dinv,
                                              u16* __restrict__ xlin, u16* __restrict__ V, int N){
  __shared__ __align__(16) u16 wb[64*STK];
  __shared__ __align__(16) u16 as[64*STK];
  int tid = threadIdx.x;
  for (int i = tid; i < 8192; i += 256){ int o = i >> 7, k = i & 127; wb[o*STK+k] = f2b(Wi[i]); }
  int nb0 = blockIdx.x*64;
  for (int i = tid; i < 8192; i += 256){
    int nn = i >> 7, k = i & 127; int n = nb0 + nn;
    as[nn*STK+k] = (n < N) ? f2b(x[(size_t)n*128 + k]) : (u16)0;
  }
  __syncthreads();
  int w = tid >> 6, lane = tid & 63;
  int m16 = lane & 15, quad = lane >> 4;
  int wbase = w*16;
  v8bf af[4];
  #pragma unroll
  for (int ks = 0; ks < 4; ks++) af[ks] = *(const v8bf*)&as[(wbase+m16)*STK + ks*32 + quad*8];
  v4f acc[4];
  #pragma unroll
  for (int ni = 0; ni < 4; ni++) acc[ni] = (v4f){0.f,0.f,0.f,0.f};
  #pragma unroll
  for (int ks = 0; ks < 4; ks++){
    #pragma unroll
    for (int ni = 0; ni < 4; ni++){
      v8bf bf = *(const v8bf*)&wb[(ni*16+m16)*STK + ks*32 + quad*8];
      acc[ni] = __builtin_amdgcn_mfma_f32_16x16x32_bf16(af[ks], bf, acc[ni], 0, 0, 0);
    }
  }
  #pragma unroll
  for (int ni = 0; ni < 4; ni++){
    int c = ni*16 + m16;
    float wc = wconv0[c], bc = bi[c];
    #pragma unroll
    for (int r = 0; r < 4; r++){
      int n = nb0 + wbase + quad*4 + r;
      if (n < N){
        float val = acc[ni][r] + bc;
        size_t idx = (size_t)n*64 + c;
        xlin[idx] = f2b(val);
        V[idx] = f2b(fmaxf(val, 0.f) * wc * dinv[idx]);
      }
    }
  }
}

// ---------------- epilogue via MFMA: residual folded as identity in Wl ----------------

__global__ __launch_bounds__(256) void epi_k(const u16* __restrict__ xlin, const float* __restrict__ dinv,
                                             float* __restrict__ U, u16* __restrict__ V,
                                             const float* __restrict__ Wl, const float* __restrict__ bconv,
                                             const float* __restrict__ wconv_next, const float* __restrict__ Wo,
                                             float* __restrict__ out, int N, int last){
  __shared__ __align__(16) u16 wb[64*STK];
  __shared__ __align__(16) u16 an[64*STK];
  int tid = threadIdx.x;
  for (int i = tid; i < 8192; i += 256){
    int o = i >> 7, c = i & 127;
    wb[o*STK+c] = f2b(Wl[i] + ((c == o) ? 1.f : 0.f));
  }
  int nb0 = blockIdx.x*64;
  for (int i = tid; i < 4096; i += 256){
    int nn = i >> 6, c = i & 63; int n = nb0 + nn;
    u16 xb = 0, gb = 0;
    if (n < N){
      size_t idx = (size_t)n*64 + c;
      xb = xlin[idx];
      float g = dinv[idx]*(b2f(V[idx]) + U[idx]) + bconv[c];
      gb = f2b(g);
      if (!last) U[idx] = 0.f;
    }
    an[nn*STK + c] = xb;
    an[nn*STK + 64 + c] = gb;
  }
  __syncthreads();
  int w = tid >> 6, lane = tid & 63;
  int m16 = lane & 15, quad = lane >> 4;
  int wbase = w*16;
  v8bf af[4];
  #pragma unroll
  for (int ks = 0; ks < 4; ks++) af[ks] = *(const v8bf*)&an[(wbase+m16)*STK + ks*32 + quad*8];
  v4f acc[4];
  #pragma unroll
  for (int ni = 0; ni < 4; ni++) acc[ni] = (v4f){0.f,0.f,0.f,0.f};
  #pragma unroll
  for (int ks = 0; ks < 4; ks++){
    #pragma unroll
    for (int ni = 0; ni < 4; ni++){
      v8bf bf = *(const v8bf*)&wb[(ni*16+m16)*STK + ks*32 + quad*8];
      acc[ni] = __builtin_amdgcn_mfma_f32_16x16x32_bf16(af[ks], bf, acc[ni], 0, 0, 0);
    }
  }
  if (!last){
    #pragma unroll
    for (int ni = 0; ni < 4; ni++){
      int c = ni*16 + m16;
      float wc = wconv_next[c];
      #pragma unroll
      for (int r = 0; r < 4; r++){
        int n = nb0 + wbase + quad*4 + r;
        if (n < N){
          size_t idx = (size_t)n*64 + c;
          V[idx] = f2b(fmaxf(acc[ni][r], 0.f) * wc * dinv[idx]);
        }
      }
    }
  } else {
    float part[4];
    #pragma unroll
    for (int r = 0; r < 4; r++){
      float p = 0.f;
      int rowl = wbase + quad*4 + r;
      #pragma unroll
      for (int ni = 0; ni < 4; ni++){
        int c = ni*16 + m16;
        float xl = b2f(an[rowl*STK + c]);
        float hr = fmaxf(acc[ni][r], 0.f);
        p += xl*Wo[c] + hr*Wo[64 + c];
      }
      part[r] = p;
    }
    #pragma unroll
    for (int off = 1; off < 16; off <<= 1)
      #pragma unroll
      for (int r = 0; r < 4; r++) part[r] += __shfl_xor(part[r], off, 64);
    if (m16 == 0){
      #pragma unroll
      for (int r = 0; r < 4; r++){
        int n = nb0 + wbase + quad*4 + r;
        if (n < N) out[n] = part[r];
      }
    }
  }
}

extern "C" void kernel_launch(void* const* d_in, const int* in_sizes, int n_in,
                              void* d_out, int out_size, void* d_ws, size_t ws_size,
                              hipStream_t stream){
  const float* x     = (const float*)d_in[0];
  const int*   ei    = (const int*)  d_in[1];
  const float* ea    = (const float*)d_in[2];
  const float* W1    = (const float*)d_in[3];
  const float* W2    = (const float*)d_in[4];
  const float* Wi    = (const float*)d_in[5];
  const float* bi    = (const float*)d_in[6];
  const float* wconv = (const float*)d_in[7];
  const float* bconv = (const float*)d_in[8];
  const float* Wl    = (const float*)d_in[9];
  const float* Wo    = (const float*)d_in[10];
  float* out = (float*)d_out;

  int N = in_sizes[0] / 128;
  int E = in_sizes[2] / 8;
  const int* row = ei;
  const int* col = ei + E;

  char* p = (char*)d_ws;
  auto alloc = [&](size_t nbytes){ char* r = p; p += (nbytes + 255) & ~(size_t)255; return r; };
  auto rnd = [](size_t x){ return (x + 255) & ~(size_t)255; };

  int*   counts = (int*)  alloc((size_t)N*4);
  int*   start  = (int*)  alloc((size_t)(N+1)*4);
  int*   cursor = (int*)  alloc((size_t)N*4);
  int*   bsum   = (int*)  alloc(4096);
  float* U      = (float*)alloc((size_t)N*256);
  float* dinv   = (float*)alloc((size_t)N*256);
  u16*   xlin   = (u16*)  alloc((size_t)N*128);
  u16*   V      = (u16*)  alloc((size_t)N*128);

  size_t base_used = (size_t)(p - (char*)d_ws);
  size_t Epad = ((size_t)E + 127) & ~(size_t)127;
  size_t need_slim = base_used + rnd(Epad*16) + rnd(Epad*8) + rnd(Epad*128);

  int gE   = (E + 255) / 256;
  int gA   = (E + EPB - 1) / EPB;
  int nb1  = (N + 1023) / 1024;
  int gN64 = (N + 63) / 64;
  int gNH  = (N*64 + 255) / 256;

  hipMemsetAsync(counts, 0, (size_t)N*4, stream);
  hipMemsetAsync(U, 0, (size_t)N*256, stream);

  hist_k <<<gE, 256, 0, stream>>>(col, counts, E);
  scan1_k<<<nb1, 1024, 0, stream>>>(counts, start, bsum, N);
  scan2_k<<<1, 1024, 0, stream>>>(bsum, nb1, start, N, E);
  scan3_k<<<nb1, 1024, 0, stream>>>(start, bsum, cursor, N);

  if (ws_size >= need_slim){
    u32*  eas = (u32*) alloc(Epad*16);
    int2* rp  = (int2*)alloc(Epad*8);
    u16*  ews = (u16*) alloc(Epad*128);   // [group][64 ch][32 e] bf16

    scat2_k<<<gE, 256, 0, stream>>>(row, col, ea, cursor, eas, rp, E);
    ewmlp_k<<<gA, 256, 0, stream>>>(eas, W1, W2, ews, E);

    sagg_k<0><<<gA, 256, 0, stream>>>(ews, rp, V, U, E);   // degree
    degfin_k<<<gNH, 256, 0, stream>>>(U, dinv, N*64);
    xlin_k  <<<gN64, 256, 0, stream>>>(x, Wi, bi, wconv, dinv, xlin, V, N);

    sagg_k<1><<<gA, 256, 0, stream>>>(ews, rp, V, U, E);
    epi_k   <<<gN64, 256, 0, stream>>>(xlin, dinv, U, V, Wl + 0*8192, bconv +   0, wconv +  64, Wo, out, N, 0);
    sagg_k<1><<<gA, 256, 0, stream>>>(ews, rp, V, U, E);
    epi_k   <<<gN64, 256, 0, stream>>>(xlin, dinv, U, V, Wl + 1*8192, bconv +  64, wconv + 128, Wo, out, N, 0);
    sagg_k<1><<<gA, 256, 0, stream>>>(ews, rp, V, U, E);
    epi_k   <<<gN64, 256, 0, stream>>>(xlin, dinv, U, V, Wl + 2*8192, bconv + 128, wconv      , Wo, out, N, 1);
  } else {
    u32* rec = (u32*)alloc((size_t)E*RW*4);

    scat_k <<<gE, 256, 0, stream>>>(row, col, ea, cursor, rec, E);

    agg_k<0><<<gA, 256, 0, stream>>>(rec, W1, W2, V, U, E);
    degfin_k<<<gNH, 256, 0, stream>>>(U, dinv, N*64);
    xlin_k  <<<gN64, 256, 0, stream>>>(x, Wi, bi, wconv, dinv, xlin, V, N);

    agg_k<1><<<gA, 256, 0, stream>>>(rec, W1, W2, V, U, E);
    epi_k   <<<gN64, 256, 0, stream>>>(xlin, dinv, U, V, Wl + 0*8192, bconv +   0, wconv +  64, Wo, out, N, 0);
    agg_k<1><<<gA, 256, 0, stream>>>(rec, W1, W2, V, U, E);
    epi_k   <<<gN64, 256, 0, stream>>>(xlin, dinv, U, V, Wl + 1*8192, bconv +  64, wconv + 128, Wo, out, N, 0);
    agg_k<1><<<gA, 256, 0, stream>>>(rec, W1, W2, V, U, E);
    epi_k   <<<gN64, 256, 0, stream>>>(xlin, dinv, U, V, Wl + 2*8192, bconv + 128, wconv      , Wo, out, N, 1);
  }
}

// Round 4
// 695.317 us; speedup vs baseline: 1.1891x; 1.1849x over previous
//
#include <hip/hip_runtime.h>

using u16 = unsigned short;
using u32 = unsigned int;

typedef __bf16 v8bf __attribute__((ext_vector_type(8)));
typedef float  v4f  __attribute__((ext_vector_type(4)));

#define ST  68    // u16 stride for agg stage rows (34 dwords: odd -> conflict-free columns)
#define STK 132   // u16 stride for 128-wide bf16 LDS rows
#define EPB 128   // edges per block in agg_k
#define RW  6     // record width in u32: [0..3]=ea bf16x8, [4]=src, [5]=tgt
#define T2S 34    // u16 stride of transposed ew tile rows (17 dwords, odd -> conflict-free)

// 1-instruction RNE f32->bf16 (identical rounding to manual round-to-nearest-even)
__device__ __forceinline__ u32 cvtpk(float lo, float hi){
  u32 r; asm("v_cvt_pk_bf16_f32 %0, %1, %2" : "=v"(r) : "v"(lo), "v"(hi)); return r;
}
__device__ __forceinline__ u16 f2b(float f){ return (u16)cvtpk(f, f); }
__device__ __forceinline__ float b2f(u16 b){
  u32 u = ((u32)b) << 16;
  return __builtin_bit_cast(float, u);
}

union bfu { v8bf v; u16 s[8]; u32 w[4]; };

__device__ __forceinline__ v8bf zero8(){
  bfu u;
  #pragma unroll
  for (int i = 0; i < 4; i++) u.w[i] = 0;
  return u.v;
}

// ---------------- one-time weight prep: bf16 images, pre-strided / identity-folded ----------------
// wimg:  [0..2048) = W1 image [64 rows][32 k] (k<8 real, else 0)
//        [2048..2048+64*ST) = W2 image [64 out][ST] (c<64 real, else 0)
// wiimg: dense [64][128] bf16 of Wi
// wlimg: 3 x dense [64][128] bf16 of (Wl + [I|0])
__global__ __launch_bounds__(256) void prep_k(const float* __restrict__ W1, const float* __restrict__ W2,
                                              const float* __restrict__ Wi, const float* __restrict__ Wl,
                                              u16* __restrict__ wimg, u16* __restrict__ wiimg,
                                              u16* __restrict__ wlimg){
  int i = blockIdx.x*256 + threadIdx.x;
  if (i < 2048){ int r = i >> 5, k = i & 31; wimg[i] = (k < 8) ? f2b(W1[r*8+k]) : (u16)0; }
  if (i < 64*ST){ int o = i / ST, c = i % ST; wimg[2048+i] = (c < 64) ? f2b(W2[o*64+c]) : (u16)0; }
  if (i < 8192) wiimg[i] = f2b(Wi[i]);
  if (i < 3*8192){
    int oc = i & 8191, o = oc >> 7, c = oc & 127;
    wlimg[i] = f2b(Wl[i] + ((c == o) ? 1.f : 0.f));
  }
}

// ---------------- counting sort by target ----------------

__global__ __launch_bounds__(256) void hist_k(const int* __restrict__ col, int* __restrict__ counts, int E){
  int e = blockIdx.x*256 + threadIdx.x;
  if (e < E) atomicAdd(&counts[col[e]], 1);
}

__global__ __launch_bounds__(1024) void scan1_k(const int* __restrict__ counts, int* __restrict__ start,
                                                int* __restrict__ bsum, int N){
  __shared__ int s[1024];
  int tid = threadIdx.x;
  int i = blockIdx.x*1024 + tid;
  int v = (i < N) ? counts[i] : 0;
  s[tid] = v; __syncthreads();
  for (int off = 1; off < 1024; off <<= 1){
    int t = (tid >= off) ? s[tid-off] : 0;
    __syncthreads();
    s[tid] += t;
    __syncthreads();
  }
  if (i < N) start[i] = s[tid] - v;
  if (tid == 1023) bsum[blockIdx.x] = s[1023];
}

__global__ __launch_bounds__(1024) void scan2_k(int* __restrict__ bsum, int nb, int* __restrict__ start,
                                                int N, int E){
  __shared__ int s[1024];
  int tid = threadIdx.x;
  int v = (tid < nb) ? bsum[tid] : 0;
  s[tid] = v; __syncthreads();
  for (int off = 1; off < 1024; off <<= 1){
    int t = (tid >= off) ? s[tid-off] : 0;
    __syncthreads();
    s[tid] += t;
    __syncthreads();
  }
  if (tid < nb) bsum[tid] = s[tid] - v;
  if (tid == 0) start[N] = E;
}

__global__ __launch_bounds__(1024) void scan3_k(int* __restrict__ start, const int* __restrict__ bsum,
                                                int* __restrict__ cursor, int N){
  int i = blockIdx.x*1024 + threadIdx.x;
  if (i < N){
    int v = start[i] + bsum[blockIdx.x];
    start[i] = v;
    cursor[i] = v;
  }
}

// fused scatter: one 24B record per edge {ea bf16x8, src, tgt} into sorted slot
__global__ __launch_bounds__(256) void scat_k(const int* __restrict__ row, const int* __restrict__ col,
                                              const float* __restrict__ ea, int* __restrict__ cursor,
                                              u32* __restrict__ rec, int E){
  int e = blockIdx.x*256 + threadIdx.x;
  if (e < E){
    int c = col[e];
    int s = row[e];
    const float4* eap = (const float4*)(ea + (size_t)e*8);
    float4 a0 = eap[0], a1 = eap[1];
    u32 w0 = cvtpk(a0.x, a0.y), w1 = cvtpk(a0.z, a0.w);
    u32 w2 = cvtpk(a1.x, a1.y), w3 = cvtpk(a1.z, a1.w);
    int p = atomicAdd(&cursor[c], 1);
    int2* r2 = (int2*)(rec + (size_t)p*RW);   // 8B aligned (24B stride)
    r2[0] = make_int2((int)w0, (int)w1);
    r2[1] = make_int2((int)w2, (int)w3);
    r2[2] = make_int2(s, c);
  }
}

// ---------------- fused edge-MLP (both layers MFMA) + segmented aggregation ----------------
// layer2 computes ew TRANSPOSED (D[ch][edge]) so the scan reads channel rows contiguously.

template<int MODE>   // 0: degree (xv=1)   1: layer (gather V bf16)
__global__ __launch_bounds__(256) void agg_k(const u32* __restrict__ rec, const u16* __restrict__ wimg,
                                             const u16* __restrict__ V, float* __restrict__ U, int E){
  __shared__ __align__(16) u16 stage[EPB*ST];   // ea -> t1 -> (overlay) t2 [64ch][T2S] per wave
  __shared__ __align__(16) u16 w2s[64*ST];
  __shared__ __align__(16) u16 w1s[64*32];
  __shared__ int sl[EPB], tl[EPB];
  int tid = threadIdx.x;
  int j0 = blockIdx.x*EPB;

  if (tid < EPB){
    int j = j0 + tid;
    int2 a = make_int2(0,0), b = make_int2(0,0), c = make_int2(0,0);
    if (j < E){
      const int2* r2 = (const int2*)(rec + (size_t)j*RW);
      a = r2[0]; b = r2[1]; c = r2[2];
    }
    sl[tid] = c.x;
    tl[tid] = c.y;
    *(int2*)&stage[tid*ST]     = a;
    *(int2*)&stage[tid*ST + 4] = b;
  }
  {
    // stage pre-converted weight images: plain vector copies, no converts.
    // w1s = 2048 u16 = 256 uint4; w2s = 4352 u16 = 544 uint4 (uint4 = 8 u16).
    const uint4* src = (const uint4*)wimg;
    uint4* d1 = (uint4*)w1s;
    uint4* d2 = (uint4*)w2s;
    if (tid < 256) d1[tid] = src[tid];
    for (int i = tid; i < 544; i += 256) d2[i] = src[256 + i];
  }
  __syncthreads();

  int w = tid >> 6, lane = tid & 63;
  int m16 = lane & 15, quad = lane >> 4;
  int base = w*32;

  // ---- layer 1 via MFMA (K padded 8->32; quads 1-3 zero), D[edge][ch] -> t1 in stage ----
  v8bf af1[2];
  #pragma unroll
  for (int mi = 0; mi < 2; mi++){
    af1[mi] = zero8();
    if (quad == 0){
      int rr = base + mi*16 + m16;
      int2 p0 = *(const int2*)&stage[rr*ST];
      int2 p1 = *(const int2*)&stage[rr*ST + 4];
      bfu u; u.w[0] = (u32)p0.x; u.w[1] = (u32)p0.y; u.w[2] = (u32)p1.x; u.w[3] = (u32)p1.y;
      af1[mi] = u.v;
    }
  }
  v4f acc1[2][4];
  #pragma unroll
  for (int mi = 0; mi < 2; mi++)
    #pragma unroll
    for (int ni = 0; ni < 4; ni++) acc1[mi][ni] = (v4f){0.f,0.f,0.f,0.f};
  #pragma unroll
  for (int ni = 0; ni < 4; ni++){
    v8bf bf = *(const v8bf*)&w1s[(ni*16 + m16)*32 + quad*8];
    #pragma unroll
    for (int mi = 0; mi < 2; mi++)
      acc1[mi][ni] = __builtin_amdgcn_mfma_f32_16x16x32_bf16(af1[mi], bf, acc1[mi][ni], 0, 0, 0);
  }
  #pragma unroll
  for (int mi = 0; mi < 2; mi++)
    #pragma unroll
    for (int ni = 0; ni < 4; ni++)
      #pragma unroll
      for (int r = 0; r < 4; r++)
        stage[(base + mi*16 + quad*4 + r)*ST + ni*16 + m16] = f2b(fmaxf(acc1[mi][ni][r], 0.f));

  // ---- layer 2 swapped: D[ch][edge] = W2 x t1^T ----
  // B-frags (t1 rows, contiguous) read BEFORE the t2 overlay writes the same region.
  v8bf bfr[2][2];
  #pragma unroll
  for (int ni = 0; ni < 2; ni++)
    #pragma unroll
    for (int ks = 0; ks < 2; ks++)
      bfr[ni][ks] = *(const v8bf*)&stage[(base + ni*16 + m16)*ST + ks*32 + quad*8];
  v4f acc2[4][2];
  #pragma unroll
  for (int mi = 0; mi < 4; mi++)
    #pragma unroll
    for (int ni = 0; ni < 2; ni++) acc2[mi][ni] = (v4f){0.f,0.f,0.f,0.f};
  #pragma unroll
  for (int ks = 0; ks < 2; ks++)
    #pragma unroll
    for (int mi = 0; mi < 4; mi++){
      v8bf afr = *(const v8bf*)&w2s[(mi*16 + m16)*ST + ks*32 + quad*8];
      #pragma unroll
      for (int ni = 0; ni < 2; ni++)
        acc2[mi][ni] = __builtin_amdgcn_mfma_f32_16x16x32_bf16(afr, bfr[ni][ks], acc2[mi][ni], 0, 0, 0);
    }
  // t2 tile overlays this wave's stage region: [64 ch][T2S] u16 at offset base*ST (2176 u16 exactly)
  int t2b = base*ST;
  #pragma unroll
  for (int mi = 0; mi < 4; mi++)
    #pragma unroll
    for (int ni = 0; ni < 2; ni++)
      #pragma unroll
      for (int r = 0; r < 4; r++)
        stage[t2b + (mi*16 + quad*4 + r)*T2S + ni*16 + m16] = f2b(fmaxf(acc2[mi][ni][r], 0.f));

  // ---- segmented scan over this wave's 32 sorted edges; lane = channel ----
  int lim = E - (j0 + base); if (lim > 32) lim = 32;
  const u32* t2w = (const u32*)&stage[t2b + lane*T2S];
  if (lim == 32){
    int tv = tl[base + (lane & 31)];
    int sv = sl[base + (lane & 31)];
    int tvp = __shfl_up(tv, 1, 32);
    unsigned long long bal = __ballot((lane & 31) != 0 && tv != tvp);
    u32 m = (u32)bal;                       // segment-start mask, bit q = boundary before edge q
    u32 ew[16];
    #pragma unroll
    for (int i = 0; i < 16; i++) ew[i] = t2w[i];
    float s = 0.f;
    int cur = __builtin_amdgcn_readlane(tv, 0);
    #pragma unroll
    for (int q0 = 0; q0 < 32; q0 += 8){
      float xv[8];
      #pragma unroll
      for (int qi = 0; qi < 8; qi++){
        if (MODE){
          int src = __builtin_amdgcn_readlane(sv, q0 + qi);
          xv[qi] = b2f(V[(size_t)src*64 + lane]);
        } else xv[qi] = 1.f;
      }
      #pragma unroll
      for (int qi = 0; qi < 8; qi++){
        int q = q0 + qi;
        if (m & (1u << q)){
          atomicAdd(&U[(size_t)cur*64 + lane], s); s = 0.f;
          cur = __builtin_amdgcn_readlane(tv, q);
        }
        u32 wb = ew[q >> 1];
        u32 bits = (q & 1) ? (wb & 0xffff0000u) : (wb << 16);
        s += __builtin_bit_cast(float, bits) * xv[qi];
      }
    }
    atomicAdd(&U[(size_t)cur*64 + lane], s);
  } else if (lim > 0){
    float s = 0.f;
    int cur = tl[base];
    for (int q = 0; q < lim; q++){
      float wv = b2f(stage[t2b + lane*T2S + q]);
      float xvv = MODE ? b2f(V[(size_t)sl[base+q]*64 + lane]) : 1.f;
      int t = tl[base+q];
      if (t != cur){ atomicAdd(&U[(size_t)cur*64 + lane], s); s = 0.f; cur = t; }
      s += wv*xvv;
    }
    atomicAdd(&U[(size_t)cur*64 + lane], s);
  }
}

__global__ __launch_bounds__(256) void degfin_k(float* __restrict__ U, float* __restrict__ dinv, int NH){
  int i = blockIdx.x*256 + threadIdx.x;
  if (i < NH){
    dinv[i] = rsqrtf(1.f + U[i]);
    U[i] = 0.f;
  }
}

// ---------------- xlin via MFMA: 64 nodes/block; xlin stored bf16 ----------------

__global__ __launch_bounds__(256) void xlin_k(const float* __restrict__ x, const u16* __restrict__ wiimg,
                                              const float* __restrict__ bi, const float* __restrict__ wconv0,
                                              const float* __restrict__ dinv,
                                              u16* __restrict__ xlin, u16* __restrict__ V, int N){
  __shared__ __align__(16) u16 wb[64*STK];   // Wi bf16 [o][k]
  __shared__ __align__(16) u16 as[64*STK];   // x  bf16 [node][k]
  int tid = threadIdx.x;
  // wb copy: 8192 u16 = 2048 uint2 (uint2 = 4 u16; rows 8B-aligned at stride STK)
  for (int i = tid; i < 2048; i += 256){ int o = i >> 5, c = i & 31; *(uint2*)&wb[o*STK + c*4] = ((const uint2*)wiimg)[i]; }
  int nb0 = blockIdx.x*64;
  // x staging: pair-convert via cvt_pk, store u32
  for (int i = tid; i < 4096; i += 256){
    int nn = i >> 6, k2 = i & 63; int n = nb0 + nn;
    u32 v = 0;
    if (n < N){ float2 xx = *(const float2*)&x[(size_t)n*128 + k2*2]; v = cvtpk(xx.x, xx.y); }
    *(u32*)&as[nn*STK + k2*2] = v;
  }
  __syncthreads();
  int w = tid >> 6, lane = tid & 63;
  int m16 = lane & 15, quad = lane >> 4;
  int wbase = w*16;
  v8bf af[4];
  #pragma unroll
  for (int ks = 0; ks < 4; ks++) af[ks] = *(const v8bf*)&as[(wbase+m16)*STK + ks*32 + quad*8];
  v4f acc[4];
  #pragma unroll
  for (int ni = 0; ni < 4; ni++) acc[ni] = (v4f){0.f,0.f,0.f,0.f};
  #pragma unroll
  for (int ks = 0; ks < 4; ks++){
    #pragma unroll
    for (int ni = 0; ni < 4; ni++){
      v8bf bf = *(const v8bf*)&wb[(ni*16+m16)*STK + ks*32 + quad*8];
      acc[ni] = __builtin_amdgcn_mfma_f32_16x16x32_bf16(af[ks], bf, acc[ni], 0, 0, 0);
    }
  }
  #pragma unroll
  for (int ni = 0; ni < 4; ni++){
    int c = ni*16 + m16;
    float wc = wconv0[c], bc = bi[c];
    #pragma unroll
    for (int r = 0; r < 4; r++){
      int n = nb0 + wbase + quad*4 + r;
      if (n < N){
        float val = acc[ni][r] + bc;
        size_t idx = (size_t)n*64 + c;
        xlin[idx] = f2b(val);
        V[idx] = f2b(fmaxf(val, 0.f) * wc * dinv[idx]);
      }
    }
  }
}

// ---------------- epilogue via MFMA: residual folded as identity in Wl (prep'd) ----------------

__global__ __launch_bounds__(256) void epi_k(const u16* __restrict__ xlin, const float* __restrict__ dinv,
                                             float* __restrict__ U, u16* __restrict__ V,
                                             const u16* __restrict__ wlimg, const float* __restrict__ bconv,
                                             const float* __restrict__ wconv_next, const float* __restrict__ Wo,
                                             float* __restrict__ out, int N, int last){
  __shared__ __align__(16) u16 wb[64*STK];   // (Wl + [I|0]) bf16 [o][c]
  __shared__ __align__(16) u16 an[64*STK];   // concat(x_, g) bf16 [node][c]
  int tid = threadIdx.x;
  for (int i = tid; i < 2048; i += 256){ int o = i >> 5, c = i & 31; *(uint2*)&wb[o*STK + c*4] = ((const uint2*)wlimg)[i]; }
  int nb0 = blockIdx.x*64;
  for (int i = tid; i < 4096; i += 256){
    int nn = i >> 6, c = i & 63; int n = nb0 + nn;
    u16 xb = 0, gb = 0;
    if (n < N){
      size_t idx = (size_t)n*64 + c;
      xb = xlin[idx];
      float g = dinv[idx]*(b2f(V[idx]) + U[idx]) + bconv[c];
      gb = f2b(g);
      if (!last) U[idx] = 0.f;
    }
    an[nn*STK + c] = xb;
    an[nn*STK + 64 + c] = gb;
  }
  __syncthreads();
  int w = tid >> 6, lane = tid & 63;
  int m16 = lane & 15, quad = lane >> 4;
  int wbase = w*16;
  v8bf af[4];
  #pragma unroll
  for (int ks = 0; ks < 4; ks++) af[ks] = *(const v8bf*)&an[(wbase+m16)*STK + ks*32 + quad*8];
  v4f acc[4];
  #pragma unroll
  for (int ni = 0; ni < 4; ni++) acc[ni] = (v4f){0.f,0.f,0.f,0.f};
  #pragma unroll
  for (int ks = 0; ks < 4; ks++){
    #pragma unroll
    for (int ni = 0; ni < 4; ni++){
      v8bf bf = *(const v8bf*)&wb[(ni*16+m16)*STK + ks*32 + quad*8];
      acc[ni] = __builtin_amdgcn_mfma_f32_16x16x32_bf16(af[ks], bf, acc[ni], 0, 0, 0);
    }
  }
  if (!last){
    #pragma unroll
    for (int ni = 0; ni < 4; ni++){
      int c = ni*16 + m16;
      float wc = wconv_next[c];
      #pragma unroll
      for (int r = 0; r < 4; r++){
        int n = nb0 + wbase + quad*4 + r;
        if (n < N){
          size_t idx = (size_t)n*64 + c;
          V[idx] = f2b(fmaxf(acc[ni][r], 0.f) * wc * dinv[idx]);
        }
      }
    }
  } else {
    float part[4];
    #pragma unroll
    for (int r = 0; r < 4; r++){
      float p = 0.f;
      int rowl = wbase + quad*4 + r;
      #pragma unroll
      for (int ni = 0; ni < 4; ni++){
        int c = ni*16 + m16;
        float xl = b2f(an[rowl*STK + c]);
        float hr = fmaxf(acc[ni][r], 0.f);
        p += xl*Wo[c] + hr*Wo[64 + c];
      }
      part[r] = p;
    }
    #pragma unroll
    for (int off = 1; off < 16; off <<= 1)
      #pragma unroll
      for (int r = 0; r < 4; r++) part[r] += __shfl_xor(part[r], off, 64);
    if (m16 == 0){
      #pragma unroll
      for (int r = 0; r < 4; r++){
        int n = nb0 + wbase + quad*4 + r;
        if (n < N) out[n] = part[r];
      }
    }
  }
}

extern "C" void kernel_launch(void* const* d_in, const int* in_sizes, int n_in,
                              void* d_out, int out_size, void* d_ws, size_t ws_size,
                              hipStream_t stream){
  const float* x     = (const float*)d_in[0];
  const int*   ei    = (const int*)  d_in[1];
  const float* ea    = (const float*)d_in[2];
  const float* W1    = (const float*)d_in[3];
  const float* W2    = (const float*)d_in[4];
  const float* Wi    = (const float*)d_in[5];
  const float* bi    = (const float*)d_in[6];
  const float* wconv = (const float*)d_in[7];
  const float* bconv = (const float*)d_in[8];
  const float* Wl    = (const float*)d_in[9];
  const float* Wo    = (const float*)d_in[10];
  float* out = (float*)d_out;

  int N = in_sizes[0] / 128;
  int E = in_sizes[2] / 8;
  const int* row = ei;
  const int* col = ei + E;

  char* p = (char*)d_ws;
  auto alloc = [&](size_t nbytes){ char* r = p; p += (nbytes + 255) & ~(size_t)255; return r; };

  int*   counts = (int*)  alloc((size_t)N*4);
  int*   start  = (int*)  alloc((size_t)(N+1)*4);
  int*   cursor = (int*)  alloc((size_t)N*4);
  int*   bsum   = (int*)  alloc(4096);
  u32*   rec    = (u32*)  alloc((size_t)E*RW*4);
  float* U      = (float*)alloc((size_t)N*256);
  float* dinv   = (float*)alloc((size_t)N*256);
  u16*   xlin   = (u16*)  alloc((size_t)N*128);
  u16*   V      = (u16*)  alloc((size_t)N*128);
  u16*   wimg   = (u16*)  alloc((size_t)(2048 + 64*ST)*2);
  u16*   wiimg  = (u16*)  alloc((size_t)8192*2);
  u16*   wlimg  = (u16*)  alloc((size_t)3*8192*2);

  int gE   = (E + 255) / 256;
  int gA   = (E + EPB - 1) / EPB;
  int nb1  = (N + 1023) / 1024;
  int gN64 = (N + 63) / 64;
  int gNH  = (N*64 + 255) / 256;

  hipMemsetAsync(counts, 0, (size_t)N*4, stream);
  hipMemsetAsync(U, 0, (size_t)N*256, stream);

  prep_k <<<96, 256, 0, stream>>>(W1, W2, Wi, Wl, wimg, wiimg, wlimg);
  hist_k <<<gE, 256, 0, stream>>>(col, counts, E);
  scan1_k<<<nb1, 1024, 0, stream>>>(counts, start, bsum, N);
  scan2_k<<<1, 1024, 0, stream>>>(bsum, nb1, start, N, E);
  scan3_k<<<nb1, 1024, 0, stream>>>(start, bsum, cursor, N);
  scat_k <<<gE, 256, 0, stream>>>(row, col, ea, cursor, rec, E);

  agg_k<0><<<gA, 256, 0, stream>>>(rec, wimg, V, U, E);   // degree
  degfin_k<<<gNH, 256, 0, stream>>>(U, dinv, N*64);
  xlin_k  <<<gN64, 256, 0, stream>>>(x, wiimg, bi, wconv, dinv, xlin, V, N);

  agg_k<1><<<gA, 256, 0, stream>>>(rec, wimg, V, U, E);
  epi_k   <<<gN64, 256, 0, stream>>>(xlin, dinv, U, V, wlimg + 0*8192, bconv +   0, wconv +  64, Wo, out, N, 0);
  agg_k<1><<<gA, 256, 0, stream>>>(rec, wimg, V, U, E);
  epi_k   <<<gN64, 256, 0, stream>>>(xlin, dinv, U, V, wlimg + 1*8192, bconv +  64, wconv + 128, Wo, out, N, 0);
  agg_k<1><<<gA, 256, 0, stream>>>(rec, wimg, V, U, E);
  epi_k   <<<gN64, 256, 0, stream>>>(xlin, dinv, U, V, wlimg + 2*8192, bconv + 128, wconv      , Wo, out, N, 1);
}